// Round 5
// baseline (3169.061 us; speedup 1.0000x reference)
//
#include <hip/hip_runtime.h>

#define N_B   64
#define N_T   1000
#define N_IN  80
#define N_REC 512
#define N_OUT 20
#define THR 1.0f
#define TCHUNK 64   // 64 steps -> 8 MB inj slice, stays L2/L3-hot between k_inj and k_scan

constexpr float ALPHA = 0.9512294245007140f; // exp(-1/20)
constexpr float KAPPA = 0.9512294245007140f;

// ---------------------------------------------------------------------------
// Kernel A: wT[j][r] = w_rec[r][j], diagonal zeroed. 513 rows: row 512 is all
// zeros (dummy target for spike-list padding).
// ---------------------------------------------------------------------------
__global__ void k_transpose(const float* __restrict__ w_rec, float* __restrict__ wT) {
    int i = blockIdx.x * blockDim.x + threadIdx.x;   // 0 .. 513*512-1
    if (i >= 513 * N_REC) return;
    int j = i >> 9;        // wT row  (source column), 0..512
    int r = i & 511;       // wT col  (source row)
    float v = 0.0f;
    if (j < N_REC && r != j) v = w_rec[r * N_REC + j];
    wT[i] = v;
}

// ---------------------------------------------------------------------------
// Kernel B: inj[(t-t0)*64 + b][r] = dot(x[b,t-1,:], w_in[r,:]) (masked) + noise[t,b,r]
// Noise load double-buffered one iteration ahead. Run per 64-step chunk with a
// small grid (128) so the per-block w_in register preload (160 KB) amortizes.
// ---------------------------------------------------------------------------
__global__ __launch_bounds__(512, 2) void k_inj(
    const float* __restrict__ x, const float* __restrict__ w_in,
    const float* __restrict__ noise, const int* __restrict__ seq,
    float* __restrict__ inj, int t0, int t1)
{
    const int r = threadIdx.x;
    float wreg[N_IN];
#pragma unroll
    for (int i = 0; i < N_IN; ++i) wreg[i] = w_in[r * N_IN + i];

    const int P = (t1 - t0) * N_B;
    const int stride = gridDim.x;

    auto nz = [&](int p) -> float {
        int pt = p >> 6, b = p & 63, t = t0 + pt;
        return __builtin_nontemporal_load(noise + ((size_t)t * N_B + b) * N_REC + r);
    };

    int p = blockIdx.x;
    float nxt = (p < P) ? nz(p) : 0.0f;
    for (; p < P; p += stride) {
        float acc = nxt;
        if (p + stride < P) nxt = nz(p + stride);
        int pt = p >> 6;
        int b  = p & 63;
        int t  = t0 + pt;
        if (t - 1 < seq[b]) {
            const float* xr = x + ((size_t)b * N_T + (t - 1)) * N_IN;
#pragma unroll
            for (int i = 0; i < N_IN; ++i) acc = fmaf(wreg[i], xr[i], acc);
        }
        inj[(size_t)p * N_REC + r] = acc;
    }
}

// ---------------------------------------------------------------------------
// Kernel C: sequential scan. One workgroup per batch, 512 threads (8 waves).
// Per step t, 3 barrier phases. vmcnt-drain discipline (every s_barrier drains
// all outstanding loads/stores):
//   A: spike gather for z(t-1); inj(t+1) prefetch issued AFTER the last gather
//      batch (youngest in vmcnt FIFO -> never blocks gather consumes, drains
//      cheap at B1); vo-partial matvec overlaps the gather's vmcnt waits.
//   B: pure VALU/LDS: reduce partials, v update, ballot, stage z floats.
//   C: list build + vo finalize + out_vo store (store residual drains at B3).
// ---------------------------------------------------------------------------
__global__ __launch_bounds__(512, 1) void k_scan(
    const float* __restrict__ wT, const float* __restrict__ inj,
    const float* __restrict__ w_out, float* __restrict__ out_vo,
    int t0, int t1,
    float* __restrict__ st_v, unsigned long long* __restrict__ st_zm,
    float* __restrict__ st_vo)
{
    const int b    = blockIdx.x;
    const int tid  = threadIdx.x;
    const int w    = tid >> 6;       // wave 0..7
    const int lane = tid & 63;
    const int g    = tid >> 7;       // row-group 0..3 (wave-uniform)
    const int c    = tid & 127;      // float4 chunk within row
    const unsigned long long lt = (1ull << lane) - 1ull;
    const int DUMMY = N_REC << 11;   // byte offset of the all-zero row

    __shared__ int lists[N_REC];                 // byte offsets (j<<11), padded
    __shared__ unsigned long long zm[8];
    __shared__ int pc[8];
    __shared__ float4 tmp_part[4][128];          // gather partials per group
    __shared__ float tmp2[16][21];               // vo partials [s][o], padded
    __shared__ alignas(16) float zfp[16 * 36];   // z floats, row s at s*36

    // w_out slice in registers: thread (o=tid>>4, s=tid&15) owns
    // w_out[o][s*32 .. s*32+31]  (tid < 320)
    float wvo[32];
    {
        int o = tid >> 4, s = tid & 15;
        if (tid < 320) {
#pragma unroll
            for (int i = 0; i < 32; ++i)
                wvo[i] = w_out[(size_t)o * N_REC + s * 32 + i];
        } else {
#pragma unroll
            for (int i = 0; i < 32; ++i) wvo[i] = 0.0f;
        }
    }

    float v;
    int z;
    float vo = 0.0f;
    int npad = 0;

    if (t0 == 1) {
        v = 0.0f; z = 0;    // empty list; first gather + vo-partial skipped
    } else {
        v = st_v[(size_t)b * N_REC + tid];
        unsigned long long m = st_zm[b * 8 + w];
        z = (int)((m >> lane) & 1ull);
        if (tid < 8) zm[tid] = st_zm[b * 8 + tid];
        if (tid < N_OUT) vo = st_vo[b * N_OUT + tid];
        __syncthreads();
        unsigned long long bm0 = zm[w];
        if (lane == 0) pc[w] = __popcll(bm0);
        __syncthreads();
        int basep = 0, ntot = 0;
#pragma unroll
        for (int ww = 0; ww < 8; ++ww) {
            int s_ = pc[ww];
            if (ww < w) basep += s_;
            ntot += s_;
        }
        if (z) lists[basep + __popcll(bm0 & lt)] = tid << 11;
        npad = (ntot + 31) & ~31;
        { int i = ntot + tid; if (i < npad) lists[i] = DUMMY; }
        __syncthreads();
    }

    // preload inj for t0
    float injn = __builtin_nontemporal_load(inj + ((size_t)0 * N_B + b) * N_REC + tid);

    for (int t = t0; t < t1; ++t) {
        float injv = injn;

        // ---- Phase A ----
        float4 acc; acc.x = 0.0f; acc.y = 0.0f; acc.z = 0.0f; acc.w = 0.0f;
        const int q  = npad >> 2;            // rows per group (multiple of 8)
        const int nb = q >> 3;
        float4 vA[8];
        if (q > 0) {
            // one LDS read covers the whole group's index list
            int jv  = lists[g * q + lane];
            int jv2 = (q > 64) ? lists[g * q + 64 + lane] : 0;
            const char* wb = (const char*)wT + (c << 4);
#pragma unroll
            for (int u = 0; u < 8; ++u) {
                int off = __builtin_amdgcn_readlane(jv, u);
                vA[u] = *(const float4*)(wb + off);
            }
            for (int k = 1; k < nb; ++k) {
                float4 vB[8];
#pragma unroll
                for (int u = 0; u < 8; ++u) {
                    int ug = (k << 3) + u;
                    int off = (ug < 64)
                        ? __builtin_amdgcn_readlane(jv,  ug)
                        : __builtin_amdgcn_readlane(jv2, ug - 64);
                    vB[u] = *(const float4*)(wb + off);
                }
#pragma unroll
                for (int u = 0; u < 8; ++u) {
                    acc.x += vA[u].x; acc.y += vA[u].y;
                    acc.z += vA[u].z; acc.w += vA[u].w;
                    vA[u] = vB[u];
                }
            }
        }

        // inj prefetch for t+1: issued after ALL gather loads (youngest in the
        // vmcnt FIFO) so no gather consume waits on it; drains cheap at B1.
        if (t + 1 < t1)
            injn = __builtin_nontemporal_load(
                inj + ((size_t)(t + 1 - t0) * N_B + b) * N_REC + tid);

        // vo partials for z(t-1) (zfp written in B of t-1; overlaps vmcnt waits)
        if (t > t0 && tid < 320) {
            int o = tid >> 4, s = tid & 15;
            const float4* zp = (const float4*)(zfp + s * 36);
            float sa = 0.0f;
#pragma unroll
            for (int i = 0; i < 8; ++i) {
                float4 zv = zp[i];
                sa = fmaf(wvo[4 * i + 0], zv.x, sa);
                sa = fmaf(wvo[4 * i + 1], zv.y, sa);
                sa = fmaf(wvo[4 * i + 2], zv.z, sa);
                sa = fmaf(wvo[4 * i + 3], zv.w, sa);
            }
            tmp2[s][o] = sa;
        }

        // final gather batch consume
        if (q > 0) {
#pragma unroll
            for (int u = 0; u < 8; ++u) {
                acc.x += vA[u].x; acc.y += vA[u].y;
                acc.z += vA[u].z; acc.w += vA[u].w;
            }
        }
        tmp_part[g][c] = acc;

        __syncthreads();   // B1: tmp_part/tmp2 complete; zfp & lists consumed

        // ---- Phase B: reduce + membrane update + ballot (pure VALU/LDS) ----
        {
            const float* tp = (const float*)tmp_part;
            float accn = tp[tid] + tp[512 + tid] + tp[1024 + tid] + tp[1536 + tid];
            v = ALPHA * v + accn + injv - (z ? THR : 0.0f);
            z = v > THR;
            zfp[(tid >> 5) * 36 + (tid & 31)] = z ? 1.0f : 0.0f;
        }
        unsigned long long bm = __ballot(z);
        if (lane == 0) { zm[w] = bm; pc[w] = __popcll(bm); }

        __syncthreads();   // B2: zm/pc/zfp visible (cheap drain: LDS only)

        // ---- Phase C: build spike list for z(t) + finalize vo(t-1) ----
        {
            int basep = 0, ntot = 0;
#pragma unroll
            for (int ww = 0; ww < 8; ++ww) {
                int s_ = pc[ww];
                if (ww < w) basep += s_;
                ntot += s_;
            }
            if (z) lists[basep + __popcll(bm & lt)] = tid << 11;
            int npn = (ntot + 31) & ~31;
            { int i = ntot + tid; if (i < npn) lists[i] = DUMMY; }
            npad = npn;
        }
        if (t > t0 && tid < N_OUT) {
            float s = 0.0f;
#pragma unroll
            for (int ss = 0; ss < 16; ++ss) s += tmp2[ss][tid];
            vo = KAPPA * vo + s;
            out_vo[((size_t)(t - 1) * N_B + b) * N_OUT + tid] = vo;
        }
        __syncthreads();   // B3: list complete; store residual drains here
    }

    // ---- tail: vo partials + finalize for z(t1-1) ----
    if (tid < 320) {
        int o = tid >> 4, s = tid & 15;
        const float4* zp = (const float4*)(zfp + s * 36);
        float sa = 0.0f;
#pragma unroll
        for (int i = 0; i < 8; ++i) {
            float4 zv = zp[i];
            sa = fmaf(wvo[4 * i + 0], zv.x, sa);
            sa = fmaf(wvo[4 * i + 1], zv.y, sa);
            sa = fmaf(wvo[4 * i + 2], zv.z, sa);
            sa = fmaf(wvo[4 * i + 3], zv.w, sa);
        }
        tmp2[s][o] = sa;
    }
    __syncthreads();
    if (tid < N_OUT) {
        float s = 0.0f;
#pragma unroll
        for (int ss = 0; ss < 16; ++ss) s += tmp2[ss][tid];
        vo = KAPPA * vo + s;
        out_vo[((size_t)(t1 - 1) * N_B + b) * N_OUT + tid] = vo;
        st_vo[b * N_OUT + tid] = vo;
    }

    // checkpoint state for next chunk
    st_v[(size_t)b * N_REC + tid] = v;
    if (lane == 0) st_zm[b * 8 + w] = zm[w];
}

// ---------------------------------------------------------------------------
// Kernel D: softmax over the 20 outputs; also writes the t=0 rows.
// ---------------------------------------------------------------------------
__global__ void k_softmax(const float* __restrict__ vo_seq,
                          float* __restrict__ out_sm,
                          float* __restrict__ out_vo0)
{
    int idx = blockIdx.x * blockDim.x + threadIdx.x;
    if (idx >= N_B * N_T) return;
    int b = idx / N_T;
    int t = idx - b * N_T;
    float vals[N_OUT];
    if (t == 0) {
#pragma unroll
        for (int o = 0; o < N_OUT; ++o) {
            vals[o] = 0.0f;
            out_vo0[(size_t)b * N_OUT + o] = 0.0f;   // vo[0] = zeros
        }
    } else {
#pragma unroll
        for (int o = 0; o < N_OUT; ++o)
            vals[o] = vo_seq[((size_t)t * N_B + b) * N_OUT + o];
    }
    float mx = vals[0];
#pragma unroll
    for (int o = 1; o < N_OUT; ++o) mx = fmaxf(mx, vals[o]);
    float s = 0.0f;
#pragma unroll
    for (int o = 0; o < N_OUT; ++o) { vals[o] = expf(vals[o] - mx); s += vals[o]; }
    float inv = 1.0f / s;
#pragma unroll
    for (int o = 0; o < N_OUT; ++o)
        out_sm[((size_t)b * N_T + t) * N_OUT + o] = vals[o] * inv;
}

// ---------------------------------------------------------------------------
extern "C" void kernel_launch(void* const* d_in, const int* in_sizes, int n_in,
                              void* d_out, int out_size, void* d_ws, size_t ws_size,
                              hipStream_t stream)
{
    (void)in_sizes; (void)n_in; (void)out_size;
    const float* x     = (const float*)d_in[0];
    const float* w_in  = (const float*)d_in[1];
    const float* w_rec = (const float*)d_in[2];
    const float* w_out = (const float*)d_in[3];
    const float* noise = (const float*)d_in[4];
    const int*   seq   = (const int*)d_in[5];

    float* out    = (float*)d_out;
    float* out_sm = out;                                   // (B,T,20)
    float* out_vo = out + (size_t)N_B * N_T * N_OUT;       // (T,B,20)

    char* ws = (char*)d_ws;
    float* wT = (float*)ws;
    size_t off = (size_t)513 * N_REC * sizeof(float);      // 513 rows (row 512 = zeros)
    float* st_v = (float*)(ws + off);                off += (size_t)N_B * N_REC * sizeof(float);
    unsigned long long* st_zm = (unsigned long long*)(ws + off); off += (size_t)N_B * 8 * sizeof(unsigned long long);
    float* st_vo = (float*)(ws + off);               off += (size_t)N_B * N_OUT * sizeof(float);
    off = (off + 255) & ~(size_t)255;
    float* inj = (float*)(ws + off);

    size_t avail = (ws_size > off) ? (ws_size - off) : 0;
    size_t step_bytes = (size_t)N_B * N_REC * sizeof(float);   // 128 KB per step
    long max_steps = (long)(avail / step_bytes);
    int tchunk = (int)((max_steps > (N_T - 1)) ? (N_T - 1) : max_steps);
    if (tchunk < 1) tchunk = 1;
    if (tchunk > TCHUNK) tchunk = TCHUNK;   // keep inj slice L2/L3-hot

    k_transpose<<<dim3((513 * N_REC + 255) / 256), dim3(256), 0, stream>>>(w_rec, wT);

    for (int t0 = 1; t0 < N_T; t0 += tchunk) {
        int t1 = t0 + tchunk; if (t1 > N_T) t1 = N_T;
        k_inj<<<dim3(128), dim3(512), 0, stream>>>(x, w_in, noise, seq, inj, t0, t1);
        k_scan<<<dim3(N_B), dim3(512), 0, stream>>>(wT, inj, w_out, out_vo,
                                                    t0, t1, st_v, st_zm, st_vo);
    }

    k_softmax<<<dim3((N_B * N_T + 255) / 256), dim3(256), 0, stream>>>(out_vo, out_sm, out_vo);
}